// Round 4
// baseline (567.897 us; speedup 1.0000x reference)
//
#include <hip/hip_runtime.h>
#include <hip/hip_bf16.h>

#define BB 16
#define SS 2048
#define DD 64
#define NT_TILES (SS / 128)     // 16 k-tiles per batch
#define TILE_BYTES 16384        // one prepacked tile image (K or V^T), bf16 swizzled

typedef __attribute__((ext_vector_type(8)))  unsigned short ushort8;
typedef __attribute__((ext_vector_type(8)))  __bf16 bf16x8;
typedef __attribute__((ext_vector_type(16))) float f32x16;
typedef __attribute__((ext_vector_type(4)))  unsigned int uint4v;

static __device__ __forceinline__ unsigned short f2bf(float x) {
    return __builtin_bit_cast(unsigned short, __float2bfloat16(x));
}
static __device__ __forceinline__ unsigned pk2(float a, float b) {
    return (unsigned)f2bf(a) | ((unsigned)f2bf(b) << 16);
}
union F4 { float4 v; float a[4]; };

// ---------------------------------------------------------------------------
// KV pre-pack (unchanged, verified r1-r3): fp32 K,V -> bf16 swizzled 16KB
// tile images in workspace. One block per (k-tile, batch).
// ---------------------------------------------------------------------------
__global__ __launch_bounds__(256)
void prepack_kernel(const float* __restrict__ K, const float* __restrict__ V,
                    char* __restrict__ wsK, char* __restrict__ wsV) {
    __shared__ __align__(16) char smem[32768];
    char* Ks = smem;
    char* Vs = smem + 16384;
    const int t  = threadIdx.x;
    const int kt = blockIdx.x;
    const int b  = blockIdx.y;
    const float* Kg = K + (size_t)b * SS * DD;
    const float* Vg = V + (size_t)b * SS * DD;

    #pragma unroll
    for (int j = 0; j < 4; j++) {
        const int idx = 2 * t + 512 * j;
        const int row = idx >> 4;
        const int g   = (idx & 15) >> 1;
        const float* src = Kg + (size_t)(kt * 128) * DD + (size_t)idx * 4;
        F4 fa, fb; fa.v = *(const float4*)src; fb.v = *(const float4*)(src + 4);
        ushort8 u;
        #pragma unroll
        for (int e = 0; e < 4; e++) { u[e] = f2bf(fa.a[e]); u[e + 4] = f2bf(fb.a[e]); }
        *(ushort8*)(Ks + row * 128 + ((g ^ (row & 7)) * 16)) = u;
    }
    {
        const int d0v = (t & 15) * 4;
        const int kkb = (t >> 4) * 4;
        #pragma unroll
        for (int it2 = 0; it2 < 2; it2++) {
            const int kk = kkb + 64 * it2;
            const float* src = Vg + (size_t)(kt * 128 + kk) * DD + d0v;
            F4 r0, r1, r2, r3;
            r0.v = *(const float4*)(src);
            r1.v = *(const float4*)(src + DD);
            r2.v = *(const float4*)(src + 2 * DD);
            r3.v = *(const float4*)(src + 3 * DD);
            #pragma unroll
            for (int e = 0; e < 4; e++) {
                const int d = d0v + e;
                const uint2 wv = make_uint2(pk2(r0.a[e], r1.a[e]), pk2(r2.a[e], r3.a[e]));
                *(uint2*)(Vs + d * 256 + (((kk >> 3) ^ (d & 15)) * 16) + (kk & 7) * 2) = wv;
            }
        }
    }
    __syncthreads();
    char* dK = wsK + (size_t)(b * NT_TILES + kt) * TILE_BYTES;
    char* dV = wsV + (size_t)(b * NT_TILES + kt) * TILE_BYTES;
    #pragma unroll
    for (int j = 0; j < 4; j++) {
        *(float4*)(dK + t * 16 + j * 4096) = *(const float4*)(Ks + t * 16 + j * 4096);
        *(float4*)(dV + t * 16 + j * 4096) = *(const float4*)(Vs + t * 16 + j * 4096);
    }
}

// ---------------------------------------------------------------------------
// Main kernel: fused single-pass. r3 post-mortem: the separate maskpack pass
// paid the 268MB mask-BW floor (~45us) serially on top of the sdpa kernel.
// Here the raw mask is read in-kernel with r2's proven per-lane uint4
// addressing (each lane reads exactly the 16 words it consumes; traffic
// unchanged; zero compress VALU), prefetched at distance ~1.5 iterations via
// two register sets tied to loop parity, reloaded right after consumption.
// Mask loads are nontemporal (read-once; keep K/V images L2/L3-resident).
// K frags ping-pong at distance 1 (r3-proven). No barriers in the loop.
// +32 VGPR -> launch_bounds(256,3); deep per-wave prefetch replaces TLP.
// ---------------------------------------------------------------------------
struct KTile { bf16x8 ak[4]; };
struct MTile { uint4v m[4]; };

__global__ __launch_bounds__(256, 3)
void sdpa_mfma_kernel(const float* __restrict__ Q, const char* __restrict__ wsK,
                      const char* __restrict__ wsV, const unsigned int* __restrict__ M,
                      float* __restrict__ O) {
    __shared__ __align__(16) char smem[25088];
    char* Qs = smem;                         // pre-loop only (4 KB, overlaps red)
    float* red  = (float*)smem;              // epilogue partials (24 KB)
    float* denx = (float*)(smem + 24576);    // epilogue den exchange (512 B)

    const int t    = threadIdx.x;
    const int lane = t & 63;
    const int l31  = lane & 31;
    const int half = lane >> 5;
    const int kh   = t >> 6;          // wave = k-chunk 32*kh of the 128-tile
    const int b    = blockIdx.y;
    const int q0   = blockIdx.x * 32;

    // ---- stage Q (pre-scaled by 1/temperature), swizzled bf16 ----
    {
        const int sr = t >> 3, sc = t & 7;
        const float* src = Q + ((size_t)b * SS + q0 + sr) * DD + sc * 8;
        F4 f0, f1; f0.v = *(const float4*)src; f1.v = *(const float4*)(src + 4);
        ushort8 u;
        #pragma unroll
        for (int e = 0; e < 4; e++) {
            u[e]     = f2bf(f0.a[e] * 0.125f);
            u[e + 4] = f2bf(f1.a[e] * 0.125f);
        }
        *(ushort8*)(Qs + sr * 128 + ((sc ^ (sr & 7)) * 16)) = u;
    }
    __syncthreads();

    const int qrow = l31;
    bf16x8 bq[4];
    #pragma unroll
    for (int dc = 0; dc < 4; dc++)
        bq[dc] = __builtin_bit_cast(bf16x8, *(const ushort8*)(
            Qs + qrow * 128 + (((2 * dc + half) ^ (qrow & 7)) * 16)));
    // (no barrier: smem untouched until the epilogue barrier)

    f32x16 On0, On1;
    #pragma unroll
    for (int i = 0; i < 16; i++) { On0[i] = 0.f; On1[i] = 0.f; }
    float den0 = 0.f, den1 = 0.f;

    const int krow = 32 * kh + l31;
    const char* tKbase = wsK + (size_t)b * NT_TILES * TILE_BYTES;
    const char* tVbase = wsV + (size_t)b * NT_TILES * TILE_BYTES;
    // raw-mask row pointer (word units): row q0+l31, cols 32kh + 4half + ...
    // (r2-proven mapping: word g component e <-> k-col 32kh + 4half + 8g + e,
    //  matching p[4g+e] / C-row = e + 8g + 4half exactly)
    const unsigned int* Mrow = M + (size_t)b * SS * SS + (size_t)(q0 + qrow) * SS
                                 + 32 * kh + 4 * half;

    auto load_kt = [&](KTile& T, int kt) {
        const char* tK = tKbase + (size_t)kt * TILE_BYTES;
        #pragma unroll
        for (int dc = 0; dc < 4; dc++)
            T.ak[dc] = __builtin_bit_cast(bf16x8, *(const ushort8*)(
                tK + krow * 128 + (((2 * dc + half) ^ (krow & 7)) * 16)));
    };
    auto load_m = [&](MTile& T, int kt) {
        #pragma unroll
        for (int g = 0; g < 4; g++)
            T.m[g] = __builtin_nontemporal_load(
                (const uint4v*)(Mrow + (size_t)kt * 128 + 8 * g));
    };

    auto tile_body = [&](const KTile& cur, KTile& nxt, MTile& mt,
                         const char* tV, int ktnK, int ktnM) {
        // V frags first: L2 latency hides under QK^T + exp below
        bf16x8 av[2][2];
        #pragma unroll
        for (int s2 = 0; s2 < 2; s2++)
            #pragma unroll
            for (int dc = 0; dc < 2; dc++) {
                const int vrow = 32 * dc + l31;
                av[s2][dc] = __builtin_bit_cast(bf16x8, *(const ushort8*)(
                    tV + vrow * 256 + (((4 * kh + 2 * s2 + half) ^ (vrow & 15)) * 16)));
            }
        // prefetch next tile's K frags (distance 1)
        load_kt(nxt, ktnK);

        // QK^T: S^T tile [32k x 32q]
        f32x16 S;
        #pragma unroll
        for (int i = 0; i < 16; i++) S[i] = 0.f;
        #pragma unroll
        for (int dc = 0; dc < 4; dc++)
            S = __builtin_amdgcn_mfma_f32_32x32x16_bf16(cur.ak[dc], bq[dc], S, 0, 0, 0);

        // mask + exp + denominator (C row = e + 8g + 4half)
        float p[16];
        #pragma unroll
        for (int g = 0; g < 4; g++) {
            #pragma unroll
            for (int e = 0; e < 4; e++) {
                const float ev = __expf(S[4 * g + e]);
                const float pv = mt.m[g][e] ? 1.0f : ev;
                p[4 * g + e] = pv;
                if (g & 1) den1 += pv; else den0 += pv;
            }
        }
        // mask regs consumed -> reload same set for tile ktnM (distance ~1.5
        // iters; WAR on the registers enforces issue-after-consume order)
        load_m(mt, ktnM);

        // P*V: B-operand frags via shfl_xor(32), 2 ksubs
        #pragma unroll
        for (int s2 = 0; s2 < 2; s2++) {
            const unsigned o0 = pk2(p[8 * s2 + 0], p[8 * s2 + 1]);
            const unsigned o1 = pk2(p[8 * s2 + 2], p[8 * s2 + 3]);
            const unsigned o2 = pk2(p[8 * s2 + 4], p[8 * s2 + 5]);
            const unsigned o3 = pk2(p[8 * s2 + 6], p[8 * s2 + 7]);
            const unsigned s0 = half ? o0 : o2;
            const unsigned s1 = half ? o1 : o3;
            const unsigned r0 = (unsigned)__shfl_xor((int)s0, 32, 64);
            const unsigned r1 = (unsigned)__shfl_xor((int)s1, 32, 64);
            uint4 bu;
            bu.x = half ? r0 : o0;
            bu.y = half ? r1 : o1;
            bu.z = half ? o2 : r0;
            bu.w = half ? o3 : r1;
            const bf16x8 bp = __builtin_bit_cast(bf16x8, bu);
            On0 = __builtin_amdgcn_mfma_f32_32x32x16_bf16(av[s2][0], bp, On0, 0, 0, 0);
            On1 = __builtin_amdgcn_mfma_f32_32x32x16_bf16(av[s2][1], bp, On1, 0, 0, 0);
        }
    };

    KTile KA, KB;
    MTile MA, MB;
    load_kt(KA, 0);
    load_m(MA, 0);
    load_m(MB, 1);
    #pragma unroll 1
    for (int kt = 0; kt < NT_TILES; kt += 2) {
        const int kA = (kt + 2 < NT_TILES) ? (kt + 2) : (NT_TILES - 1); // clamp: dead load
        const int kB = (kt + 3 < NT_TILES) ? (kt + 3) : (NT_TILES - 1);
        tile_body(KA, KB, MA, tVbase + (size_t)kt * TILE_BYTES, kt + 1, kA);
        tile_body(KB, KA, MB, tVbase + (size_t)(kt + 1) * TILE_BYTES, kA, kB);
    }

    // ---- epilogue: lane halves, then 4-way k-split reduction via LDS ----
    const float den_acc = den0 + den1;
    const float den_tot = den_acc + __shfl_xor(den_acc, 32, 64);

    __syncthreads();
    if (kh != 0) {
        #pragma unroll
        for (int dc = 0; dc < 2; dc++)
            #pragma unroll
            for (int g = 0; g < 4; g++) {
                const f32x16& Oc = dc ? On1 : On0;
                float4 st;
                st.x = Oc[4 * g + 0]; st.y = Oc[4 * g + 1];
                st.z = Oc[4 * g + 2]; st.w = Oc[4 * g + 3];
                *(float4*)((char*)red + (kh - 1) * 8192 + (dc * 4 + g) * 1024 + lane * 16) = st;
            }
        if (lane < 32) denx[kh * 32 + l31] = den_tot;
    }
    __syncthreads();
    if (kh == 0) {
        const float inv = 1.0f / (den_tot + denx[32 + l31] + denx[64 + l31] + denx[96 + l31]);
        float* Og = O + ((size_t)b * SS + q0 + qrow) * DD;
        #pragma unroll
        for (int dc = 0; dc < 2; dc++)
            #pragma unroll
            for (int g = 0; g < 4; g++) {
                const f32x16& Oc = dc ? On1 : On0;
                float4 st;
                st.x = Oc[4 * g + 0]; st.y = Oc[4 * g + 1];
                st.z = Oc[4 * g + 2]; st.w = Oc[4 * g + 3];
                #pragma unroll
                for (int w2 = 0; w2 < 3; w2++) {
                    const float4 pr = *(const float4*)((char*)red + w2 * 8192 +
                                                       (dc * 4 + g) * 1024 + lane * 16);
                    st.x += pr.x; st.y += pr.y; st.z += pr.z; st.w += pr.w;
                }
                st.x *= inv; st.y *= inv; st.z *= inv; st.w *= inv;
                // d = e + 8g + 4half + 32dc  (C-row formula)
                *(float4*)(Og + 32 * dc + 8 * g + 4 * half) = st;
            }
    }
}

extern "C" void kernel_launch(void* const* d_in, const int* in_sizes, int n_in,
                              void* d_out, int out_size, void* d_ws, size_t ws_size,
                              hipStream_t stream) {
    const float* q = (const float*)d_in[0];
    const float* k = (const float*)d_in[1];
    const float* v = (const float*)d_in[2];
    const unsigned int* m = (const unsigned int*)d_in[3];
    float* out = (float*)d_out;

    // workspace: 4 MB K images + 4 MB V images (bf16, swizzled tile layout)
    char* wsK = (char*)d_ws;
    char* wsV = wsK + (size_t)BB * NT_TILES * TILE_BYTES;

    dim3 pgrid(NT_TILES, BB);           // 256 blocks
    prepack_kernel<<<pgrid, 256, 0, stream>>>(k, v, wsK, wsV);

    dim3 grid(SS / 32, BB);             // 1024 blocks
    sdpa_mfma_kernel<<<grid, 256, 0, stream>>>(q, wsK, wsV, m, out);
}

// Round 5
// 415.846 us; speedup vs baseline: 1.3656x; 1.3656x over previous
//
#include <hip/hip_runtime.h>
#include <hip/hip_bf16.h>

#define BB 16
#define SS 2048
#define DD 64
#define NT_TILES (SS / 128)     // 16 k-tiles per batch
#define TILE_BYTES 16384        // one prepacked tile image (K or V^T), bf16 swizzled

typedef __attribute__((ext_vector_type(8)))  unsigned short ushort8;
typedef __attribute__((ext_vector_type(8)))  __bf16 bf16x8;
typedef __attribute__((ext_vector_type(16))) float f32x16;
typedef __attribute__((ext_vector_type(4)))  unsigned int uint4v;

static __device__ __forceinline__ unsigned short f2bf(float x) {
    return __builtin_bit_cast(unsigned short, __float2bfloat16(x));
}
static __device__ __forceinline__ unsigned pk2(float a, float b) {
    return (unsigned)f2bf(a) | ((unsigned)f2bf(b) << 16);
}
union F4 { float4 v; float a[4]; };

// width-16 async global->LDS copy. LDS dest = wave-uniform base + lane*16;
// global src is per-lane. Fire-and-forget: no VGPR held, compiler cannot
// sink it (r2/r4 post-mortem: register prefetch gets sunk; this doesn't).
#define GLDS16(src, dst) __builtin_amdgcn_global_load_lds(                 \
    (const __attribute__((address_space(1))) unsigned int*)(src),          \
    (__attribute__((address_space(3))) unsigned int*)(dst), 16, 0, 0)

// ---------------------------------------------------------------------------
// KV pre-pack (unchanged, verified r1-r4): fp32 K,V -> bf16 swizzled 16KB
// tile images in workspace. One block per (k-tile, batch).
// ---------------------------------------------------------------------------
__global__ __launch_bounds__(256)
void prepack_kernel(const float* __restrict__ K, const float* __restrict__ V,
                    char* __restrict__ wsK, char* __restrict__ wsV) {
    __shared__ __align__(16) char smem[32768];
    char* Ks = smem;
    char* Vs = smem + 16384;
    const int t  = threadIdx.x;
    const int kt = blockIdx.x;
    const int b  = blockIdx.y;
    const float* Kg = K + (size_t)b * SS * DD;
    const float* Vg = V + (size_t)b * SS * DD;

    #pragma unroll
    for (int j = 0; j < 4; j++) {
        const int idx = 2 * t + 512 * j;
        const int row = idx >> 4;
        const int g   = (idx & 15) >> 1;
        const float* src = Kg + (size_t)(kt * 128) * DD + (size_t)idx * 4;
        F4 fa, fb; fa.v = *(const float4*)src; fb.v = *(const float4*)(src + 4);
        ushort8 u;
        #pragma unroll
        for (int e = 0; e < 4; e++) { u[e] = f2bf(fa.a[e]); u[e + 4] = f2bf(fb.a[e]); }
        *(ushort8*)(Ks + row * 128 + ((g ^ (row & 7)) * 16)) = u;
    }
    {
        const int d0v = (t & 15) * 4;
        const int kkb = (t >> 4) * 4;
        #pragma unroll
        for (int it2 = 0; it2 < 2; it2++) {
            const int kk = kkb + 64 * it2;
            const float* src = Vg + (size_t)(kt * 128 + kk) * DD + d0v;
            F4 r0, r1, r2, r3;
            r0.v = *(const float4*)(src);
            r1.v = *(const float4*)(src + DD);
            r2.v = *(const float4*)(src + 2 * DD);
            r3.v = *(const float4*)(src + 3 * DD);
            #pragma unroll
            for (int e = 0; e < 4; e++) {
                const int d = d0v + e;
                const uint2 wv = make_uint2(pk2(r0.a[e], r1.a[e]), pk2(r2.a[e], r3.a[e]));
                *(uint2*)(Vs + d * 256 + (((kk >> 3) ^ (d & 15)) * 16) + (kk & 7) * 2) = wv;
            }
        }
    }
    __syncthreads();
    char* dK = wsK + (size_t)(b * NT_TILES + kt) * TILE_BYTES;
    char* dV = wsV + (size_t)(b * NT_TILES + kt) * TILE_BYTES;
    #pragma unroll
    for (int j = 0; j < 4; j++) {
        *(float4*)(dK + t * 16 + j * 4096) = *(const float4*)(Ks + t * 16 + j * 4096);
        *(float4*)(dV + t * 16 + j * 4096) = *(const float4*)(Vs + t * 16 + j * 4096);
    }
}

// ---------------------------------------------------------------------------
// Main kernel. Mask pipeline (the 268MB stream, the whole bottleneck):
// per-WAVE self-contained LDS staging, NO barriers. Wave kh needs exactly
// mask cols 32kh..+31 x rows q0..q0+31 = 4KB/tile; it stages its own region
// with 4x global_load_lds (per-lane src: instr j covers rows 8j..8j+7, 8
// lanes x 16B per 128B row chunk -> fully coalesced). Triple buffer =
// distance 2 (~2 bodies >> HBM latency). Ordering = one counted
// "s_waitcnt vmcnt(8)" + sched_barrier per tile (m201/m218 pattern: counted,
// never a drain). Source-side XOR swizzle (rule #21) so readback
// ds_read_b128 is balanced 8-way across banks instead of 32-way.
// K/V frag reads (L2-resident images) and all compute: r3/r4-verified code.
// ---------------------------------------------------------------------------
struct KTile { bf16x8 ak[4]; };

__global__ __launch_bounds__(256, 3)
void sdpa_mfma_kernel(const float* __restrict__ Q, const char* __restrict__ wsK,
                      const char* __restrict__ wsV, const unsigned int* __restrict__ M,
                      float* __restrict__ O) {
    // layout: [0..48K) mask bufs (3 x 16KB, per-buf: 4 waves x 4KB)
    // Qs aliases buf0 (pre-loop only, barrier-separated);
    // epilogue red (24KB) + denx alias bufs (post-loop, barrier-separated)
    __shared__ __align__(16) char smem[49152];
    char* Qs = smem;
    float* red  = (float*)smem;
    float* denx = (float*)(smem + 24576);

    const int t    = threadIdx.x;
    const int lane = t & 63;
    const int l31  = lane & 31;
    const int half = lane >> 5;
    const int kh   = t >> 6;          // wave = k-chunk 32*kh of the 128-tile
    const int b    = blockIdx.y;
    const int q0   = blockIdx.x * 32;

    // ---- stage Q (pre-scaled by 1/temperature), swizzled bf16 ----
    {
        const int sr = t >> 3, sc = t & 7;
        const float* src = Q + ((size_t)b * SS + q0 + sr) * DD + sc * 8;
        F4 f0, f1; f0.v = *(const float4*)src; f1.v = *(const float4*)(src + 4);
        ushort8 u;
        #pragma unroll
        for (int e = 0; e < 4; e++) {
            u[e]     = f2bf(f0.a[e] * 0.125f);
            u[e + 4] = f2bf(f1.a[e] * 0.125f);
        }
        *(ushort8*)(Qs + sr * 128 + ((sc ^ (sr & 7)) * 16)) = u;
    }
    __syncthreads();

    const int qrow = l31;
    bf16x8 bq[4];
    #pragma unroll
    for (int dc = 0; dc < 4; dc++)
        bq[dc] = __builtin_bit_cast(bf16x8, *(const ushort8*)(
            Qs + qrow * 128 + (((2 * dc + half) ^ (qrow & 7)) * 16)));
    __syncthreads();   // Qs region becomes mask buf0 after this barrier

    f32x16 On0, On1;
    #pragma unroll
    for (int i = 0; i < 16; i++) { On0[i] = 0.f; On1[i] = 0.f; }
    float den0 = 0.f, den1 = 0.f;

    const int krow = 32 * kh + l31;
    const char* tKbase = wsK + (size_t)b * NT_TILES * TILE_BYTES;
    const char* tVbase = wsV + (size_t)b * NT_TILES * TILE_BYTES;

    // per-lane mask staging src: instr j covers rows q0+8j+(lane>>3),
    // 16B chunk at col 32kh + 4*((lane&7)^(lane>>3))  (inverse swizzle so
    // the LINEAR LDS dest holds the swizzled image; (row&7) == lane>>3)
    const unsigned int* Msrc = M + (size_t)b * SS * SS
                                 + (size_t)(q0 + (lane >> 3)) * SS
                                 + 32 * kh + 4 * ((lane & 7) ^ (lane >> 3));
    char* const wbase = smem + kh * 4096;   // this wave's region within a buf

    auto stage = [&](int bufn, int kt) {
        const unsigned int* src = Msrc + (size_t)kt * 128;
        char* dst = wbase + bufn * 16384;
        #pragma unroll
        for (int j = 0; j < 4; j++)
            GLDS16(src + (size_t)j * 8 * SS, dst + j * 1024);
    };

    auto load_kt = [&](KTile& T, int kt) {
        const char* tK = tKbase + (size_t)kt * TILE_BYTES;
        #pragma unroll
        for (int dc = 0; dc < 4; dc++)
            T.ak[dc] = __builtin_bit_cast(bf16x8, *(const ushort8*)(
                tK + krow * 128 + (((2 * dc + half) ^ (krow & 7)) * 16)));
    };

    const int r7 = l31 & 7;

    auto tile_body = [&](const KTile& cur, KTile& nxt, int kt, int ktS, int ktnK) {
        // stage mask for tile ktS (== kt+2 clamped) into buf (kt+2)%3
        stage((kt + 2) % 3, ktS);
        // counted wait: outstanding = batches kt+1, kt+2 (4 each) -> kt done.
        // Never drains; loads for kt+1/kt+2 stay in flight (T4 discipline).
        asm volatile("s_waitcnt vmcnt(8)" ::: "memory");
        __builtin_amdgcn_sched_barrier(0);

        // readback this wave's mask words for tile kt (swizzled granules):
        // mt[g][e] <-> col 32kh + 4half + 8g + e  (r2-proven mapping)
        uint4v mt[4];
        const char* mb = smem + (kt % 3) * 16384 + kh * 4096 + l31 * 128;
        #pragma unroll
        for (int g = 0; g < 4; g++)
            mt[g] = *(const uint4v*)(mb + 16 * ((half + 2 * g) ^ r7));

        // V frags (L2-resident image): latency hides under QK^T below
        const char* tV = tVbase + (size_t)kt * TILE_BYTES;
        bf16x8 av[2][2];
        #pragma unroll
        for (int s2 = 0; s2 < 2; s2++)
            #pragma unroll
            for (int dc = 0; dc < 2; dc++) {
                const int vrow = 32 * dc + l31;
                av[s2][dc] = __builtin_bit_cast(bf16x8, *(const ushort8*)(
                    tV + vrow * 256 + (((4 * kh + 2 * s2 + half) ^ (vrow & 15)) * 16)));
            }
        load_kt(nxt, ktnK);

        // QK^T: S^T tile [32k x 32q]
        f32x16 S;
        #pragma unroll
        for (int i = 0; i < 16; i++) S[i] = 0.f;
        #pragma unroll
        for (int dc = 0; dc < 4; dc++)
            S = __builtin_amdgcn_mfma_f32_32x32x16_bf16(cur.ak[dc], bq[dc], S, 0, 0, 0);

        // mask + exp + denominator (C row = e + 8g + 4half)
        float p[16];
        #pragma unroll
        for (int g = 0; g < 4; g++) {
            #pragma unroll
            for (int e = 0; e < 4; e++) {
                const float ev = __expf(S[4 * g + e]);
                const float pv = mt[g][e] ? 1.0f : ev;
                p[4 * g + e] = pv;
                if (g & 1) den1 += pv; else den0 += pv;
            }
        }

        // P*V: B-operand frags via shfl_xor(32), 2 ksubs (r0-proven)
        #pragma unroll
        for (int s2 = 0; s2 < 2; s2++) {
            const unsigned o0 = pk2(p[8 * s2 + 0], p[8 * s2 + 1]);
            const unsigned o1 = pk2(p[8 * s2 + 2], p[8 * s2 + 3]);
            const unsigned o2 = pk2(p[8 * s2 + 4], p[8 * s2 + 5]);
            const unsigned o3 = pk2(p[8 * s2 + 6], p[8 * s2 + 7]);
            const unsigned s0 = half ? o0 : o2;
            const unsigned s1 = half ? o1 : o3;
            const unsigned r0 = (unsigned)__shfl_xor((int)s0, 32, 64);
            const unsigned r1 = (unsigned)__shfl_xor((int)s1, 32, 64);
            uint4 bu;
            bu.x = half ? r0 : o0;
            bu.y = half ? r1 : o1;
            bu.z = half ? o2 : r0;
            bu.w = half ? o3 : r1;
            const bf16x8 bp = __builtin_bit_cast(bf16x8, bu);
            On0 = __builtin_amdgcn_mfma_f32_32x32x16_bf16(av[s2][0], bp, On0, 0, 0, 0);
            On1 = __builtin_amdgcn_mfma_f32_32x32x16_bf16(av[s2][1], bp, On1, 0, 0, 0);
        }
    };

    KTile KA, KB;
    load_kt(KA, 0);
    stage(0, 0);        // prologue: 2 batches in flight before first body
    stage(1, 1);
    #pragma unroll 1
    for (int kt = 0; kt < NT_TILES; kt += 2) {
        const int kA = (kt + 2 < NT_TILES) ? (kt + 2) : (NT_TILES - 1); // clamp: tail
        const int kB = (kt + 3 < NT_TILES) ? (kt + 3) : (NT_TILES - 1); // re-stages are
        tile_body(KA, KB, kt,     kA, kt + 1);  // dead-but-counted (vmcnt math holds;
        tile_body(KB, KA, kt + 1, kB, kA);      // target buf != consumed buf: (x+2)%3 != x%3)
    }

    // ---- epilogue: lane halves, then 4-way k-split reduction via LDS ----
    const float den_acc = den0 + den1;
    const float den_tot = den_acc + __shfl_xor(den_acc, 32, 64);

    __syncthreads();   // drains all in-flight stages; bufs become red/denx
    if (kh != 0) {
        #pragma unroll
        for (int dc = 0; dc < 2; dc++)
            #pragma unroll
            for (int g = 0; g < 4; g++) {
                const f32x16& Oc = dc ? On1 : On0;
                float4 st;
                st.x = Oc[4 * g + 0]; st.y = Oc[4 * g + 1];
                st.z = Oc[4 * g + 2]; st.w = Oc[4 * g + 3];
                *(float4*)((char*)red + (kh - 1) * 8192 + (dc * 4 + g) * 1024 + lane * 16) = st;
            }
        if (lane < 32) denx[kh * 32 + l31] = den_tot;
    }
    __syncthreads();
    if (kh == 0) {
        const float inv = 1.0f / (den_tot + denx[32 + l31] + denx[64 + l31] + denx[96 + l31]);
        float* Og = O + ((size_t)b * SS + q0 + qrow) * DD;
        #pragma unroll
        for (int dc = 0; dc < 2; dc++)
            #pragma unroll
            for (int g = 0; g < 4; g++) {
                const f32x16& Oc = dc ? On1 : On0;
                float4 st;
                st.x = Oc[4 * g + 0]; st.y = Oc[4 * g + 1];
                st.z = Oc[4 * g + 2]; st.w = Oc[4 * g + 3];
                #pragma unroll
                for (int w2 = 0; w2 < 3; w2++) {
                    const float4 pr = *(const float4*)((char*)red + w2 * 8192 +
                                                       (dc * 4 + g) * 1024 + lane * 16);
                    st.x += pr.x; st.y += pr.y; st.z += pr.z; st.w += pr.w;
                }
                st.x *= inv; st.y *= inv; st.z *= inv; st.w *= inv;
                // d = e + 8g + 4half + 32dc  (C-row formula)
                *(float4*)(Og + 32 * dc + 8 * g + 4 * half) = st;
            }
    }
}

extern "C" void kernel_launch(void* const* d_in, const int* in_sizes, int n_in,
                              void* d_out, int out_size, void* d_ws, size_t ws_size,
                              hipStream_t stream) {
    const float* q = (const float*)d_in[0];
    const float* k = (const float*)d_in[1];
    const float* v = (const float*)d_in[2];
    const unsigned int* m = (const unsigned int*)d_in[3];
    float* out = (float*)d_out;

    // workspace: 4 MB K images + 4 MB V images (bf16, swizzled tile layout)
    char* wsK = (char*)d_ws;
    char* wsV = wsK + (size_t)BB * NT_TILES * TILE_BYTES;

    dim3 pgrid(NT_TILES, BB);           // 256 blocks
    prepack_kernel<<<pgrid, 256, 0, stream>>>(k, v, wsK, wsV);

    dim3 grid(SS / 32, BB);             // 1024 blocks -> 3 per CU (LDS-capped)
    sdpa_mfma_kernel<<<grid, 256, 0, stream>>>(q, wsK, wsV, m, out);
}

// Round 6
// 393.841 us; speedup vs baseline: 1.4419x; 1.0559x over previous
//
#include <hip/hip_runtime.h>
#include <hip/hip_bf16.h>

#define BB 16
#define SS 2048
#define DD 64
#define NT_TILES (SS / 128)     // 16 k-tiles per batch
#define TILE_BYTES 16384        // one prepacked tile image (K or V^T), bf16 swizzled
#define BUF_BYTES 49152         // one LDS tile buffer: 4 waves x 12KB (K4|V4|M4)

typedef __attribute__((ext_vector_type(8)))  unsigned short ushort8;
typedef __attribute__((ext_vector_type(8)))  __bf16 bf16x8;
typedef __attribute__((ext_vector_type(16))) float f32x16;
typedef __attribute__((ext_vector_type(4)))  unsigned int uint4v;

static __device__ __forceinline__ unsigned short f2bf(float x) {
    return __builtin_bit_cast(unsigned short, __float2bfloat16(x));
}
static __device__ __forceinline__ unsigned pk2(float a, float b) {
    return (unsigned)f2bf(a) | ((unsigned)f2bf(b) << 16);
}
union F4 { float4 v; float a[4]; };

// width-16 async global->LDS copy. LDS dest = wave-uniform base + lane*16;
// global src is per-lane. Fire-and-forget (vmcnt domain only).
#define GLDS16(src, dst) __builtin_amdgcn_global_load_lds(                 \
    (const __attribute__((address_space(1))) unsigned int*)(src),          \
    (__attribute__((address_space(3))) unsigned int*)(dst), 16, 0, 0)

// ---------------------------------------------------------------------------
// KV pre-pack (unchanged, verified r1-r5): fp32 K,V -> bf16 swizzled 16KB
// tile images in workspace. One block per (k-tile, batch).
// ---------------------------------------------------------------------------
__global__ __launch_bounds__(256)
void prepack_kernel(const float* __restrict__ K, const float* __restrict__ V,
                    char* __restrict__ wsK, char* __restrict__ wsV) {
    __shared__ __align__(16) char smem[32768];
    char* Ks = smem;
    char* Vs = smem + 16384;
    const int t  = threadIdx.x;
    const int kt = blockIdx.x;
    const int b  = blockIdx.y;
    const float* Kg = K + (size_t)b * SS * DD;
    const float* Vg = V + (size_t)b * SS * DD;

    #pragma unroll
    for (int j = 0; j < 4; j++) {
        const int idx = 2 * t + 512 * j;
        const int row = idx >> 4;
        const int g   = (idx & 15) >> 1;
        const float* src = Kg + (size_t)(kt * 128) * DD + (size_t)idx * 4;
        F4 fa, fb; fa.v = *(const float4*)src; fb.v = *(const float4*)(src + 4);
        ushort8 u;
        #pragma unroll
        for (int e = 0; e < 4; e++) { u[e] = f2bf(fa.a[e]); u[e + 4] = f2bf(fb.a[e]); }
        *(ushort8*)(Ks + row * 128 + ((g ^ (row & 7)) * 16)) = u;
    }
    {
        const int d0v = (t & 15) * 4;
        const int kkb = (t >> 4) * 4;
        #pragma unroll
        for (int it2 = 0; it2 < 2; it2++) {
            const int kk = kkb + 64 * it2;
            const float* src = Vg + (size_t)(kt * 128 + kk) * DD + d0v;
            F4 r0, r1, r2, r3;
            r0.v = *(const float4*)(src);
            r1.v = *(const float4*)(src + DD);
            r2.v = *(const float4*)(src + 2 * DD);
            r3.v = *(const float4*)(src + 3 * DD);
            #pragma unroll
            for (int e = 0; e < 4; e++) {
                const int d = d0v + e;
                const uint2 wv = make_uint2(pk2(r0.a[e], r1.a[e]), pk2(r2.a[e], r3.a[e]));
                *(uint2*)(Vs + d * 256 + (((kk >> 3) ^ (d & 15)) * 16) + (kk & 7) * 2) = wv;
            }
        }
    }
    __syncthreads();
    char* dK = wsK + (size_t)(b * NT_TILES + kt) * TILE_BYTES;
    char* dV = wsV + (size_t)(b * NT_TILES + kt) * TILE_BYTES;
    #pragma unroll
    for (int j = 0; j < 4; j++) {
        *(float4*)(dK + t * 16 + j * 4096) = *(const float4*)(Ks + t * 16 + j * 4096);
        *(float4*)(dV + t * 16 + j * 4096) = *(const float4*)(Vs + t * 16 + j * 4096);
    }
}

// ---------------------------------------------------------------------------
// Main kernel. r5 post-mortem: vmcnt retires IN ISSUE ORDER, so any
// compiler-inserted wait for a register K/V load drained the older HBM mask
// stages -> full HBM latency exposed per tile. Fix: HOMOGENEOUS VMEM stream.
// ALL operands (K slice, V slice, mask slice) go global_load_lds -> ds_read;
// the loop's only VMEM waits are my counted vmcnt(24) (= 2 batches of 12 in
// flight, distance-2 triple buffer). Zero barriers in the loop (buffers are
// wave-private and disjoint). 144KB LDS -> 1 block/CU, 4 waves; the fill
// kernels prove 84% HBM at ~10% occupancy, and this loop is mask-BW-bound
// (compute floor ~23us < mask stream 268MB ~ 45us).
// Per-wave per-tile slices (disjoint, union = full tile):
//   K: image rows 32kh..32kh+31 = contiguous 4KB -> linear copy, read with
//      the image's own (row&7) XOR granule swizzle (bank-balanced).
//   V: logical granules 4kh..4kh+3 (k=32kh..+31) of all 64 d-rows; per-lane
//      src extracts them from the image's (d&15) XOR layout; stored LOGICAL
//      in LDS: bufV[d*64 + s*16], read at (2s2+half).
//   M: r5-verified path (inverse-swizzled src, linear dest, XOR read).
// ---------------------------------------------------------------------------
__global__ __launch_bounds__(256, 1)
void sdpa_mfma_kernel(const float* __restrict__ Q, const char* __restrict__ wsK,
                      const char* __restrict__ wsV, const unsigned int* __restrict__ M,
                      float* __restrict__ O) {
    __shared__ __align__(16) char smem[3 * BUF_BYTES];   // 144 KB
    char* Qs = smem;                         // pre-loop only (4 KB, barrier-fenced)
    float* red  = (float*)smem;              // epilogue partials (24 KB, in buf0)
    float* denx = (float*)(smem + 24576);    // epilogue den exchange (512 B)

    const int t    = threadIdx.x;
    const int lane = t & 63;
    const int l31  = lane & 31;
    const int half = lane >> 5;
    const int kh   = t >> 6;          // wave = k-chunk 32*kh of the 128-tile
    const int b    = blockIdx.y;
    const int q0   = blockIdx.x * 32;

    // ---- stage Q (pre-scaled by 1/temperature), swizzled bf16 ----
    {
        const int sr = t >> 3, sc = t & 7;
        const float* src = Q + ((size_t)b * SS + q0 + sr) * DD + sc * 8;
        F4 f0, f1; f0.v = *(const float4*)src; f1.v = *(const float4*)(src + 4);
        ushort8 u;
        #pragma unroll
        for (int e = 0; e < 4; e++) {
            u[e]     = f2bf(f0.a[e] * 0.125f);
            u[e + 4] = f2bf(f1.a[e] * 0.125f);
        }
        *(ushort8*)(Qs + sr * 128 + ((sc ^ (sr & 7)) * 16)) = u;
    }
    __syncthreads();

    const int qrow = l31;
    bf16x8 bq[4];
    #pragma unroll
    for (int dc = 0; dc < 4; dc++)
        bq[dc] = __builtin_bit_cast(bf16x8, *(const ushort8*)(
            Qs + qrow * 128 + (((2 * dc + half) ^ (qrow & 7)) * 16)));
    __syncthreads();   // all bq reads done before any wave's stage overwrites Qs

    f32x16 On0, On1;
    #pragma unroll
    for (int i = 0; i < 16; i++) { On0[i] = 0.f; On1[i] = 0.f; }
    float den0 = 0.f, den1 = 0.f;

    const char* tKbase = wsK + (size_t)b * NT_TILES * TILE_BYTES;
    const char* tVbase = wsV + (size_t)b * NT_TILES * TILE_BYTES;

    // mask staging src (r5-verified): instr j covers rows q0+8j+(lane>>3),
    // 16B chunk at col 32kh + 4*((lane&7)^(lane>>3)) (inverse swizzle)
    const unsigned int* Msrc = M + (size_t)b * SS * SS
                                 + (size_t)(q0 + (lane >> 3)) * SS
                                 + 32 * kh + 4 * ((lane & 7) ^ (lane >> 3));
    // V staging src per-lane offset: instr j covers d = 16j + (lane>>2);
    // logical s = lane&3 sits at image granule pos (4kh+s)^(d&15):
    //   byte = d*256 + (kh^((d>>2)&3))*64 + ((s^(d&3))*16)
    const int voff = ((lane >> 2) * 256)
                   + ((kh ^ ((lane >> 4) & 3)) * 64)
                   + (((lane & 3) ^ ((lane >> 2) & 3)) * 16);
    const int r7 = l31 & 7;

    auto stage = [&](int bufn, int kt) {
        char* wb = smem + bufn * BUF_BYTES + kh * 12288;
        const char* tK = tKbase + (size_t)kt * TILE_BYTES + 32 * kh * 128;
        #pragma unroll
        for (int j = 0; j < 4; j++)                       // K: linear 4KB slice
            GLDS16(tK + j * 1024 + lane * 16, wb + j * 1024);
        const char* tV = tVbase + (size_t)kt * TILE_BYTES;
        #pragma unroll
        for (int j = 0; j < 4; j++)                       // V: granule extract
            GLDS16(tV + j * 4096 + voff, wb + 4096 + j * 1024);
        const unsigned int* ms = Msrc + (size_t)kt * 128;
        #pragma unroll
        for (int j = 0; j < 4; j++)                       // M: r5-verified
            GLDS16(ms + (size_t)j * 8 * SS, wb + 8192 + j * 1024);
    };

    stage(0, 0);          // prologue: 2 tile batches in flight
    stage(1, 1);

    #pragma unroll 1
    for (int kt = 0; kt < NT_TILES; ++kt) {
        const int ktS = (kt + 2 < NT_TILES) ? kt + 2 : NT_TILES - 1; // tail: dead
        stage((kt + 2) % 3, ktS);                                    // re-stage
        // counted wait: allow the 2 newest batches (24 glds) in flight;
        // batch kt is complete. Never drains (T4 discipline).
        asm volatile("s_waitcnt vmcnt(24)" ::: "memory");
        __builtin_amdgcn_sched_barrier(0);

        const char* wb = smem + (kt % 3) * BUF_BYTES + kh * 12288;

        // K frags (image-swizzled slice; local row = l31)
        bf16x8 ak[4];
        #pragma unroll
        for (int dc = 0; dc < 4; dc++)
            ak[dc] = __builtin_bit_cast(bf16x8, *(const ushort8*)(
                wb + l31 * 128 + (((2 * dc + half) ^ r7) * 16)));
        // mask words (r5-verified mapping): mt[g][e] <-> col 32kh+4half+8g+e
        uint4v mt[4];
        #pragma unroll
        for (int g = 0; g < 4; g++)
            mt[g] = *(const uint4v*)(wb + 8192 + l31 * 128 + 16 * ((half + 2 * g) ^ r7));
        // V frags (logical layout)
        bf16x8 av[2][2];
        #pragma unroll
        for (int s2 = 0; s2 < 2; s2++)
            #pragma unroll
            for (int dc = 0; dc < 2; dc++) {
                const int vrow = 32 * dc + l31;
                av[s2][dc] = __builtin_bit_cast(bf16x8, *(const ushort8*)(
                    wb + 4096 + vrow * 64 + (2 * s2 + half) * 16));
            }

        // QK^T: S^T tile [32k x 32q]
        f32x16 S;
        #pragma unroll
        for (int i = 0; i < 16; i++) S[i] = 0.f;
        #pragma unroll
        for (int dc = 0; dc < 4; dc++)
            S = __builtin_amdgcn_mfma_f32_32x32x16_bf16(ak[dc], bq[dc], S, 0, 0, 0);

        // mask + exp + denominator (C row = e + 8g + 4half)
        float p[16];
        #pragma unroll
        for (int g = 0; g < 4; g++) {
            #pragma unroll
            for (int e = 0; e < 4; e++) {
                const float ev = __expf(S[4 * g + e]);
                const float pv = mt[g][e] ? 1.0f : ev;
                p[4 * g + e] = pv;
                if (g & 1) den1 += pv; else den0 += pv;
            }
        }

        // P*V: B-operand frags via shfl_xor(32), 2 ksubs (r0-proven)
        #pragma unroll
        for (int s2 = 0; s2 < 2; s2++) {
            const unsigned o0 = pk2(p[8 * s2 + 0], p[8 * s2 + 1]);
            const unsigned o1 = pk2(p[8 * s2 + 2], p[8 * s2 + 3]);
            const unsigned o2 = pk2(p[8 * s2 + 4], p[8 * s2 + 5]);
            const unsigned o3 = pk2(p[8 * s2 + 6], p[8 * s2 + 7]);
            const unsigned s0 = half ? o0 : o2;
            const unsigned s1 = half ? o1 : o3;
            const unsigned r0 = (unsigned)__shfl_xor((int)s0, 32, 64);
            const unsigned r1 = (unsigned)__shfl_xor((int)s1, 32, 64);
            uint4 bu;
            bu.x = half ? r0 : o0;
            bu.y = half ? r1 : o1;
            bu.z = half ? o2 : r0;
            bu.w = half ? o3 : r1;
            const bf16x8 bp = __builtin_bit_cast(bf16x8, bu);
            On0 = __builtin_amdgcn_mfma_f32_32x32x16_bf16(av[s2][0], bp, On0, 0, 0, 0);
            On1 = __builtin_amdgcn_mfma_f32_32x32x16_bf16(av[s2][1], bp, On1, 0, 0, 0);
        }
    }

    // ---- epilogue: lane halves, then 4-way k-split reduction via LDS ----
    const float den_acc = den0 + den1;
    const float den_tot = den_acc + __shfl_xor(den_acc, 32, 64);

    __syncthreads();   // drains all in-flight stages (dead tails hit buf1/buf2 only)
    if (kh != 0) {
        #pragma unroll
        for (int dc = 0; dc < 2; dc++)
            #pragma unroll
            for (int g = 0; g < 4; g++) {
                const f32x16& Oc = dc ? On1 : On0;
                float4 st;
                st.x = Oc[4 * g + 0]; st.y = Oc[4 * g + 1];
                st.z = Oc[4 * g + 2]; st.w = Oc[4 * g + 3];
                *(float4*)((char*)red + (kh - 1) * 8192 + (dc * 4 + g) * 1024 + lane * 16) = st;
            }
        if (lane < 32) denx[kh * 32 + l31] = den_tot;
    }
    __syncthreads();
    if (kh == 0) {
        const float inv = 1.0f / (den_tot + denx[32 + l31] + denx[64 + l31] + denx[96 + l31]);
        float* Og = O + ((size_t)b * SS + q0 + qrow) * DD;
        #pragma unroll
        for (int dc = 0; dc < 2; dc++)
            #pragma unroll
            for (int g = 0; g < 4; g++) {
                const f32x16& Oc = dc ? On1 : On0;
                float4 st;
                st.x = Oc[4 * g + 0]; st.y = Oc[4 * g + 1];
                st.z = Oc[4 * g + 2]; st.w = Oc[4 * g + 3];
                #pragma unroll
                for (int w2 = 0; w2 < 3; w2++) {
                    const float4 pr = *(const float4*)((char*)red + w2 * 8192 +
                                                       (dc * 4 + g) * 1024 + lane * 16);
                    st.x += pr.x; st.y += pr.y; st.z += pr.z; st.w += pr.w;
                }
                st.x *= inv; st.y *= inv; st.z *= inv; st.w *= inv;
                // d = e + 8g + 4half + 32dc  (C-row formula)
                *(float4*)(Og + 32 * dc + 8 * g + 4 * half) = st;
            }
    }
}

extern "C" void kernel_launch(void* const* d_in, const int* in_sizes, int n_in,
                              void* d_out, int out_size, void* d_ws, size_t ws_size,
                              hipStream_t stream) {
    const float* q = (const float*)d_in[0];
    const float* k = (const float*)d_in[1];
    const float* v = (const float*)d_in[2];
    const unsigned int* m = (const unsigned int*)d_in[3];
    float* out = (float*)d_out;

    // workspace: 4 MB K images + 4 MB V images (bf16, swizzled tile layout)
    char* wsK = (char*)d_ws;
    char* wsV = wsK + (size_t)BB * NT_TILES * TILE_BYTES;

    dim3 pgrid(NT_TILES, BB);           // 256 blocks
    prepack_kernel<<<pgrid, 256, 0, stream>>>(k, v, wsK, wsV);

    dim3 grid(SS / 32, BB);             // 1024 blocks -> 1 per CU (144KB LDS), 4 rounds
    sdpa_mfma_kernel<<<grid, 256, 0, stream>>>(q, wsK, wsV, m, out);
}

// Round 7
// 382.127 us; speedup vs baseline: 1.4861x; 1.0307x over previous
//
#include <hip/hip_runtime.h>
#include <hip/hip_bf16.h>

#define BB 16
#define SS 2048
#define DD 64
#define NT_TILES (SS / 128)     // 16 k-tiles per batch
#define TILE_BYTES 16384        // one prepacked tile image (K or V^T), bf16 swizzled
#define KVBUF 32768             // one KV buffer: K 16K (4 kh slices) + V 16K
#define MBUF  32768             // one M buffer: 8 waves x 4KB

typedef __attribute__((ext_vector_type(8)))  unsigned short ushort8;
typedef __attribute__((ext_vector_type(8)))  __bf16 bf16x8;
typedef __attribute__((ext_vector_type(16))) float f32x16;
typedef __attribute__((ext_vector_type(4)))  unsigned int uint4v;

static __device__ __forceinline__ unsigned short f2bf(float x) {
    return __builtin_bit_cast(unsigned short, __float2bfloat16(x));
}
static __device__ __forceinline__ unsigned pk2(float a, float b) {
    return (unsigned)f2bf(a) | ((unsigned)f2bf(b) << 16);
}
union F4 { float4 v; float a[4]; };

// width-16 async global->LDS copy. LDS dest = wave-uniform base + lane*16;
// global src is per-lane. Fire-and-forget (vmcnt domain only).
#define GLDS16(src, dst) __builtin_amdgcn_global_load_lds(                 \
    (const __attribute__((address_space(1))) unsigned int*)(src),          \
    (__attribute__((address_space(3))) unsigned int*)(dst), 16, 0, 0)

// ---------------------------------------------------------------------------
// KV pre-pack (unchanged, verified r1-r6): fp32 K,V -> bf16 swizzled 16KB
// tile images in workspace. One block per (k-tile, batch).
// ---------------------------------------------------------------------------
__global__ __launch_bounds__(256)
void prepack_kernel(const float* __restrict__ K, const float* __restrict__ V,
                    char* __restrict__ wsK, char* __restrict__ wsV) {
    __shared__ __align__(16) char smem[32768];
    char* Ks = smem;
    char* Vs = smem + 16384;
    const int t  = threadIdx.x;
    const int kt = blockIdx.x;
    const int b  = blockIdx.y;
    const float* Kg = K + (size_t)b * SS * DD;
    const float* Vg = V + (size_t)b * SS * DD;

    #pragma unroll
    for (int j = 0; j < 4; j++) {
        const int idx = 2 * t + 512 * j;
        const int row = idx >> 4;
        const int g   = (idx & 15) >> 1;
        const float* src = Kg + (size_t)(kt * 128) * DD + (size_t)idx * 4;
        F4 fa, fb; fa.v = *(const float4*)src; fb.v = *(const float4*)(src + 4);
        ushort8 u;
        #pragma unroll
        for (int e = 0; e < 4; e++) { u[e] = f2bf(fa.a[e]); u[e + 4] = f2bf(fb.a[e]); }
        *(ushort8*)(Ks + row * 128 + ((g ^ (row & 7)) * 16)) = u;
    }
    {
        const int d0v = (t & 15) * 4;
        const int kkb = (t >> 4) * 4;
        #pragma unroll
        for (int it2 = 0; it2 < 2; it2++) {
            const int kk = kkb + 64 * it2;
            const float* src = Vg + (size_t)(kt * 128 + kk) * DD + d0v;
            F4 r0, r1, r2, r3;
            r0.v = *(const float4*)(src);
            r1.v = *(const float4*)(src + DD);
            r2.v = *(const float4*)(src + 2 * DD);
            r3.v = *(const float4*)(src + 3 * DD);
            #pragma unroll
            for (int e = 0; e < 4; e++) {
                const int d = d0v + e;
                const uint2 wv = make_uint2(pk2(r0.a[e], r1.a[e]), pk2(r2.a[e], r3.a[e]));
                *(uint2*)(Vs + d * 256 + (((kk >> 3) ^ (d & 15)) * 16) + (kk & 7) * 2) = wv;
            }
        }
    }
    __syncthreads();
    char* dK = wsK + (size_t)(b * NT_TILES + kt) * TILE_BYTES;
    char* dV = wsV + (size_t)(b * NT_TILES + kt) * TILE_BYTES;
    #pragma unroll
    for (int j = 0; j < 4; j++) {
        *(float4*)(dK + t * 16 + j * 4096) = *(const float4*)(Ks + t * 16 + j * 4096);
        *(float4*)(dV + t * 16 + j * 4096) = *(const float4*)(Vs + t * 16 + j * 4096);
    }
}

// ---------------------------------------------------------------------------
// Main kernel. r6 post-mortem: correct pipeline, but 144KB LDS -> 1 wave/SIMD
// -> latency-serial compute (ds 120cy + 4-deep MFMA chains + 16 exp) can't
// interleave; body ~2900cy vs 1600cy BW floor. Fix: 8 waves (2 q-subtiles x
// 4 kh) sharing K/V stages across q-pairs -> 2 waves/SIMD at 160KB LDS.
//   LDS: KV dbuf 2x32KB (K 16K + V 16K, shared) + M tbuf 3x32KB (private).
//   Per body kt (lockstep via RAW s_barrier, no drain):
//     1. s_waitcnt vmcnt(4)   -> retires M(kt) [2-body cushion, HBM] and
//        KV(kt) [1-body cushion, L2]; only M(kt+1) stays in flight.
//     2. s_barrier            -> kt-data cross-wave visible; kt-1 bufs free.
//     3. stage KV(kt+1) [qs=0: K slice, qs=1: V slice; 4 glds, L2]
//     4. stage M(kt+2) [4 glds, HBM, wave-private]
//     5. consume kt (r5/r6-verified ds_read formulas + compute).
//   vmcnt math: issue order ... KV(kt+1) < M(kt+2); at next wait the newest
//   4 = M batch only, so vmcnt(4) is exact. 8 glds/wave/body.
// ---------------------------------------------------------------------------
__global__ __launch_bounds__(512, 1)
void sdpa_mfma_kernel(const float* __restrict__ Q, const char* __restrict__ wsK,
                      const char* __restrict__ wsV, const unsigned int* __restrict__ M,
                      float* __restrict__ O) {
    __shared__ __align__(16) char smem[2 * KVBUF + 3 * MBUF];   // 160 KB exactly
    char* Qs = smem;                         // 8 KB, pre-loop only (in KV buf0)
    char* const Mbase = smem + 2 * KVBUF;    // M buffers
    float* red  = (float*)smem;              // epilogue partials (48 KB)
    float* denx = (float*)(smem + 49152);    // epilogue den exchange (1 KB)

    const int t    = threadIdx.x;
    const int lane = t & 63;
    const int l31  = lane & 31;
    const int half = lane >> 5;
    const int w    = t >> 6;          // wave id 0..7
    const int kh   = w & 3;           // k-chunk 32*kh of the 128-tile
    const int qs   = w >> 2;          // q-subtile (0: rows q0.., 1: rows q0+32..)
    const int b    = blockIdx.y;
    const int q0   = blockIdx.x * 64;
    const int q0v  = q0 + 32 * qs;

    // ---- stage Q (64 rows, pre-scaled by 1/temperature), swizzled bf16 ----
    {
        const int sr = t >> 3, sc = t & 7;   // 512 thr -> 64 rows x 8 chunks
        const float* src = Q + ((size_t)b * SS + q0 + sr) * DD + sc * 8;
        F4 f0, f1; f0.v = *(const float4*)src; f1.v = *(const float4*)(src + 4);
        ushort8 u;
        #pragma unroll
        for (int e = 0; e < 4; e++) {
            u[e]     = f2bf(f0.a[e] * 0.125f);
            u[e + 4] = f2bf(f1.a[e] * 0.125f);
        }
        *(ushort8*)(Qs + sr * 128 + ((sc ^ (sr & 7)) * 16)) = u;
    }
    __syncthreads();

    const int qrow = l31;
    const int r7   = l31 & 7;
    bf16x8 bq[4];
    #pragma unroll
    for (int dc = 0; dc < 4; dc++)
        bq[dc] = __builtin_bit_cast(bf16x8, *(const ushort8*)(
            Qs + (32 * qs + qrow) * 128 + (((2 * dc + half) ^ r7) * 16)));
    __syncthreads();   // all bq reads done before prologue stages overwrite Qs

    f32x16 On0, On1;
    #pragma unroll
    for (int i = 0; i < 16; i++) { On0[i] = 0.f; On1[i] = 0.f; }
    float den0 = 0.f, den1 = 0.f;

    const char* tKbase = wsK + (size_t)b * NT_TILES * TILE_BYTES;
    const char* tVbase = wsV + (size_t)b * NT_TILES * TILE_BYTES;

    // mask staging src (r5/r6-verified): instr j covers rows q0v+8j+(lane>>3),
    // 16B chunk at col 32kh + 4*((lane&7)^(lane>>3)) (inverse swizzle)
    const unsigned int* Msrc = M + (size_t)b * SS * SS
                                 + (size_t)(q0v + (lane >> 3)) * SS
                                 + 32 * kh + 4 * ((lane & 7) ^ (lane >> 3));
    // V staging src per-lane offset (r6-verified granule extract)
    const int voff = ((lane >> 2) * 256)
                   + ((kh ^ ((lane >> 4) & 3)) * 64)
                   + (((lane & 3) ^ ((lane >> 2) & 3)) * 16);

    auto stage_kv = [&](int bufn, int kt) {
        char* kvb = smem + bufn * KVBUF;
        if (qs == 0) {      // wave-uniform branch: qs=0 waves stage K slice kh
            const char* tK = tKbase + (size_t)kt * TILE_BYTES + 32 * kh * 128;
            #pragma unroll
            for (int j = 0; j < 4; j++)
                GLDS16(tK + j * 1024 + lane * 16, kvb + kh * 4096 + j * 1024);
        } else {            // qs=1 waves stage V slice kh (granule extract)
            const char* tV = tVbase + (size_t)kt * TILE_BYTES;
            #pragma unroll
            for (int j = 0; j < 4; j++)
                GLDS16(tV + j * 4096 + voff, kvb + 16384 + kh * 4096 + j * 1024);
        }
    };
    auto stage_m = [&](int bufn, int kt) {
        char* mb = Mbase + bufn * MBUF + w * 4096;
        const unsigned int* ms = Msrc + (size_t)kt * 128;
        #pragma unroll
        for (int j = 0; j < 4; j++)
            GLDS16(ms + (size_t)j * 8 * SS, mb + j * 1024);
    };

    // prologue: KV(0), M(0), M(1) in flight (12 glds)
    stage_kv(0, 0);
    stage_m(0, 0);
    stage_m(1, 1);

    #pragma unroll 1
    for (int kt = 0; kt < NT_TILES; ++kt) {
        // 1. counted wait: newest 4 = M(kt+1); retires M(kt) + KV(kt).
        asm volatile("s_waitcnt vmcnt(4)" ::: "memory");
        __builtin_amdgcn_sched_barrier(0);
        // 2. raw barrier (no drain): kt data visible, kt-1 buffers free
        __builtin_amdgcn_s_barrier();
        // 3./4. stages (dead clamped tails target non-live buffers)
        const int kKV = (kt + 1 < NT_TILES) ? kt + 1 : NT_TILES - 1;
        const int kM  = (kt + 2 < NT_TILES) ? kt + 2 : NT_TILES - 1;
        stage_kv((kt + 1) & 1, kKV);
        stage_m((kt + 2) % 3, kM);

        // 5. consume tile kt
        const char* kvb = smem + (kt & 1) * KVBUF;
        const char* mb  = Mbase + (kt % 3) * MBUF + w * 4096;

        bf16x8 ak[4];
        #pragma unroll
        for (int dc = 0; dc < 4; dc++)
            ak[dc] = __builtin_bit_cast(bf16x8, *(const ushort8*)(
                kvb + kh * 4096 + l31 * 128 + (((2 * dc + half) ^ r7) * 16)));
        uint4v mt[4];
        #pragma unroll
        for (int g = 0; g < 4; g++)
            mt[g] = *(const uint4v*)(mb + l31 * 128 + 16 * ((half + 2 * g) ^ r7));
        bf16x8 av[2][2];
        #pragma unroll
        for (int s2 = 0; s2 < 2; s2++)
            #pragma unroll
            for (int dc = 0; dc < 2; dc++) {
                const int vrow = 32 * dc + l31;
                av[s2][dc] = __builtin_bit_cast(bf16x8, *(const ushort8*)(
                    kvb + 16384 + kh * 4096 + vrow * 64 + (2 * s2 + half) * 16));
            }

        // QK^T: S^T tile [32k x 32q]
        f32x16 S;
        #pragma unroll
        for (int i = 0; i < 16; i++) S[i] = 0.f;
        #pragma unroll
        for (int dc = 0; dc < 4; dc++)
            S = __builtin_amdgcn_mfma_f32_32x32x16_bf16(ak[dc], bq[dc], S, 0, 0, 0);

        // mask + exp + denominator (C row = e + 8g + 4half)
        float p[16];
        #pragma unroll
        for (int g = 0; g < 4; g++) {
            #pragma unroll
            for (int e = 0; e < 4; e++) {
                const float ev = __expf(S[4 * g + e]);
                const float pv = mt[g][e] ? 1.0f : ev;
                p[4 * g + e] = pv;
                if (g & 1) den1 += pv; else den0 += pv;
            }
        }

        // P*V: B-operand frags via shfl_xor(32), 2 ksubs (r0-proven)
        #pragma unroll
        for (int s2 = 0; s2 < 2; s2++) {
            const unsigned o0 = pk2(p[8 * s2 + 0], p[8 * s2 + 1]);
            const unsigned o1 = pk2(p[8 * s2 + 2], p[8 * s2 + 3]);
            const unsigned o2 = pk2(p[8 * s2 + 4], p[8 * s2 + 5]);
            const unsigned o3 = pk2(p[8 * s2 + 6], p[8 * s2 + 7]);
            const unsigned s0 = half ? o0 : o2;
            const unsigned s1 = half ? o1 : o3;
            const unsigned r0 = (unsigned)__shfl_xor((int)s0, 32, 64);
            const unsigned r1 = (unsigned)__shfl_xor((int)s1, 32, 64);
            uint4 bu;
            bu.x = half ? r0 : o0;
            bu.y = half ? r1 : o1;
            bu.z = half ? o2 : r0;
            bu.w = half ? o3 : r1;
            const bf16x8 bp = __builtin_bit_cast(bf16x8, bu);
            On0 = __builtin_amdgcn_mfma_f32_32x32x16_bf16(av[s2][0], bp, On0, 0, 0, 0);
            On1 = __builtin_amdgcn_mfma_f32_32x32x16_bf16(av[s2][1], bp, On1, 0, 0, 0);
        }
    }

    // ---- epilogue: lane halves, then 4-way kh reduction per qs group ----
    const float den_acc = den0 + den1;
    const float den_tot = den_acc + __shfl_xor(den_acc, 32, 64);

    __syncthreads();   // full drain (incl. dead tail stages); bufs -> red/denx
    if (kh != 0) {
        #pragma unroll
        for (int dc = 0; dc < 2; dc++)
            #pragma unroll
            for (int g = 0; g < 4; g++) {
                const f32x16& Oc = dc ? On1 : On0;
                float4 st;
                st.x = Oc[4 * g + 0]; st.y = Oc[4 * g + 1];
                st.z = Oc[4 * g + 2]; st.w = Oc[4 * g + 3];
                *(float4*)((char*)red + qs * 24576 + (kh - 1) * 8192 +
                           (dc * 4 + g) * 1024 + lane * 16) = st;
            }
        if (lane < 32) denx[w * 32 + l31] = den_tot;
    }
    __syncthreads();
    if (kh == 0) {
        const float inv = 1.0f / (den_tot + denx[(qs * 4 + 1) * 32 + l31]
                                          + denx[(qs * 4 + 2) * 32 + l31]
                                          + denx[(qs * 4 + 3) * 32 + l31]);
        float* Og = O + ((size_t)b * SS + q0v + qrow) * DD;
        #pragma unroll
        for (int dc = 0; dc < 2; dc++)
            #pragma unroll
            for (int g = 0; g < 4; g++) {
                const f32x16& Oc = dc ? On1 : On0;
                float4 st;
                st.x = Oc[4 * g + 0]; st.y = Oc[4 * g + 1];
                st.z = Oc[4 * g + 2]; st.w = Oc[4 * g + 3];
                #pragma unroll
                for (int w2 = 0; w2 < 3; w2++) {
                    const float4 pr = *(const float4*)((char*)red + qs * 24576 +
                                        w2 * 8192 + (dc * 4 + g) * 1024 + lane * 16);
                    st.x += pr.x; st.y += pr.y; st.z += pr.z; st.w += pr.w;
                }
                st.x *= inv; st.y *= inv; st.z *= inv; st.w *= inv;
                // d = e + 8g + 4half + 32dc  (C-row formula)
                *(float4*)(Og + 32 * dc + 8 * g + 4 * half) = st;
            }
    }
}

extern "C" void kernel_launch(void* const* d_in, const int* in_sizes, int n_in,
                              void* d_out, int out_size, void* d_ws, size_t ws_size,
                              hipStream_t stream) {
    const float* q = (const float*)d_in[0];
    const float* k = (const float*)d_in[1];
    const float* v = (const float*)d_in[2];
    const unsigned int* m = (const unsigned int*)d_in[3];
    float* out = (float*)d_out;

    // workspace: 4 MB K images + 4 MB V images (bf16, swizzled tile layout)
    char* wsK = (char*)d_ws;
    char* wsV = wsK + (size_t)BB * NT_TILES * TILE_BYTES;

    dim3 pgrid(NT_TILES, BB);           // 256 blocks
    prepack_kernel<<<pgrid, 256, 0, stream>>>(k, v, wsK, wsV);

    dim3 grid(SS / 64, BB);             // 512 blocks x 512 thr -> 1/CU, 2 rounds
    sdpa_mfma_kernel<<<grid, 512, 0, stream>>>(q, wsK, wsV, m, out);
}

// Round 8
// 381.333 us; speedup vs baseline: 1.4892x; 1.0021x over previous
//
#include <hip/hip_runtime.h>
#include <hip/hip_bf16.h>

#define BB 16
#define SS 2048
#define DD 64
#define NT_TILES (SS / 128)     // 16 k-tiles per batch
#define TILE_BYTES 16384        // one prepacked tile image (K or V^T), bf16 swizzled
#define KVBUF 32768             // one KV buffer: K 16K (4 kh slices) + V 16K
#define MBUF  32768             // one M buffer: 8 waves x 4KB

typedef __attribute__((ext_vector_type(8)))  unsigned short ushort8;
typedef __attribute__((ext_vector_type(8)))  __bf16 bf16x8;
typedef __attribute__((ext_vector_type(16))) float f32x16;
typedef __attribute__((ext_vector_type(4)))  unsigned int uint4v;

static __device__ __forceinline__ unsigned short f2bf(float x) {
    return __builtin_bit_cast(unsigned short, __float2bfloat16(x));
}
static __device__ __forceinline__ unsigned pk2(float a, float b) {
    return (unsigned)f2bf(a) | ((unsigned)f2bf(b) << 16);
}
union F4 { float4 v; float a[4]; };

// width-16 async global->LDS copy. LDS dest = wave-uniform base + lane*16;
// global src is per-lane. Fire-and-forget (vmcnt domain only).
#define GLDS16(src, dst) __builtin_amdgcn_global_load_lds(                 \
    (const __attribute__((address_space(1))) unsigned int*)(src),          \
    (__attribute__((address_space(3))) unsigned int*)(dst), 16, 0, 0)

// ---------------------------------------------------------------------------
// KV pre-pack (unchanged, verified r1-r7): fp32 K,V -> bf16 swizzled 16KB
// tile images in workspace. One block per (k-tile, batch).
// ---------------------------------------------------------------------------
__global__ __launch_bounds__(256)
void prepack_kernel(const float* __restrict__ K, const float* __restrict__ V,
                    char* __restrict__ wsK, char* __restrict__ wsV) {
    __shared__ __align__(16) char smem[32768];
    char* Ks = smem;
    char* Vs = smem + 16384;
    const int t  = threadIdx.x;
    const int kt = blockIdx.x;
    const int b  = blockIdx.y;
    const float* Kg = K + (size_t)b * SS * DD;
    const float* Vg = V + (size_t)b * SS * DD;

    #pragma unroll
    for (int j = 0; j < 4; j++) {
        const int idx = 2 * t + 512 * j;
        const int row = idx >> 4;
        const int g   = (idx & 15) >> 1;
        const float* src = Kg + (size_t)(kt * 128) * DD + (size_t)idx * 4;
        F4 fa, fb; fa.v = *(const float4*)src; fb.v = *(const float4*)(src + 4);
        ushort8 u;
        #pragma unroll
        for (int e = 0; e < 4; e++) { u[e] = f2bf(fa.a[e]); u[e + 4] = f2bf(fb.a[e]); }
        *(ushort8*)(Ks + row * 128 + ((g ^ (row & 7)) * 16)) = u;
    }
    {
        const int d0v = (t & 15) * 4;
        const int kkb = (t >> 4) * 4;
        #pragma unroll
        for (int it2 = 0; it2 < 2; it2++) {
            const int kk = kkb + 64 * it2;
            const float* src = Vg + (size_t)(kt * 128 + kk) * DD + d0v;
            F4 r0, r1, r2, r3;
            r0.v = *(const float4*)(src);
            r1.v = *(const float4*)(src + DD);
            r2.v = *(const float4*)(src + 2 * DD);
            r3.v = *(const float4*)(src + 3 * DD);
            #pragma unroll
            for (int e = 0; e < 4; e++) {
                const int d = d0v + e;
                const uint2 wv = make_uint2(pk2(r0.a[e], r1.a[e]), pk2(r2.a[e], r3.a[e]));
                *(uint2*)(Vs + d * 256 + (((kk >> 3) ^ (d & 15)) * 16) + (kk & 7) * 2) = wv;
            }
        }
    }
    __syncthreads();
    char* dK = wsK + (size_t)(b * NT_TILES + kt) * TILE_BYTES;
    char* dV = wsV + (size_t)(b * NT_TILES + kt) * TILE_BYTES;
    #pragma unroll
    for (int j = 0; j < 4; j++) {
        *(float4*)(dK + t * 16 + j * 4096) = *(const float4*)(Ks + t * 16 + j * 4096);
        *(float4*)(dV + t * 16 + j * 4096) = *(const float4*)(Vs + t * 16 + j * 4096);
    }
}

// ---------------------------------------------------------------------------
// Main kernel (r7 structure, verified: 8 waves = 2 qs x 4 kh, shared KV dbuf
// + private M tbuf, counted vmcnt(4) + raw s_barrier lockstep, zero drains).
// r7 post-mortem: SQ_LDS_BANK_CONFLICT=5.3M, all from the V fragment read:
// 64B lane pitch put 16 lanes on 4 banks (4x serialization, ~1.1Kcy of a
// 3.2Kcy body). Fix: V slot XOR-swizzle with (d>>1)&3 (both-sides involution,
// rule 21): SOURCE pre-swizzle in voff (glds dest stays linear) + slot XOR on
// the read. Uniform 8 dwords/bank over the wave -> conflict-free b128.
// ---------------------------------------------------------------------------
__global__ __launch_bounds__(512, 1)
void sdpa_mfma_kernel(const float* __restrict__ Q, const char* __restrict__ wsK,
                      const char* __restrict__ wsV, const unsigned int* __restrict__ M,
                      float* __restrict__ O) {
    __shared__ __align__(16) char smem[2 * KVBUF + 3 * MBUF];   // 160 KB exactly
    char* Qs = smem;                         // 8 KB, pre-loop only (in KV buf0)
    char* const Mbase = smem + 2 * KVBUF;    // M buffers
    float* red  = (float*)smem;              // epilogue partials (48 KB)
    float* denx = (float*)(smem + 49152);    // epilogue den exchange (1 KB)

    const int t    = threadIdx.x;
    const int lane = t & 63;
    const int l31  = lane & 31;
    const int half = lane >> 5;
    const int w    = t >> 6;          // wave id 0..7
    const int kh   = w & 3;           // k-chunk 32*kh of the 128-tile
    const int qs   = w >> 2;          // q-subtile (0: rows q0.., 1: rows q0+32..)
    const int b    = blockIdx.y;
    const int q0   = blockIdx.x * 64;
    const int q0v  = q0 + 32 * qs;

    // ---- stage Q (64 rows, pre-scaled by 1/temperature), swizzled bf16 ----
    {
        const int sr = t >> 3, sc = t & 7;   // 512 thr -> 64 rows x 8 chunks
        const float* src = Q + ((size_t)b * SS + q0 + sr) * DD + sc * 8;
        F4 f0, f1; f0.v = *(const float4*)src; f1.v = *(const float4*)(src + 4);
        ushort8 u;
        #pragma unroll
        for (int e = 0; e < 4; e++) {
            u[e]     = f2bf(f0.a[e] * 0.125f);
            u[e + 4] = f2bf(f1.a[e] * 0.125f);
        }
        *(ushort8*)(Qs + sr * 128 + ((sc ^ (sr & 7)) * 16)) = u;
    }
    __syncthreads();

    const int qrow = l31;
    const int r7   = l31 & 7;
    bf16x8 bq[4];
    #pragma unroll
    for (int dc = 0; dc < 4; dc++)
        bq[dc] = __builtin_bit_cast(bf16x8, *(const ushort8*)(
            Qs + (32 * qs + qrow) * 128 + (((2 * dc + half) ^ r7) * 16)));
    __syncthreads();   // all bq reads done before prologue stages overwrite Qs

    f32x16 On0, On1;
    #pragma unroll
    for (int i = 0; i < 16; i++) { On0[i] = 0.f; On1[i] = 0.f; }
    float den0 = 0.f, den1 = 0.f;

    const char* tKbase = wsK + (size_t)b * NT_TILES * TILE_BYTES;
    const char* tVbase = wsV + (size_t)b * NT_TILES * TILE_BYTES;

    // mask staging src (r5-r7 verified): instr j covers rows q0v+8j+(lane>>3),
    // 16B chunk at col 32kh + 4*((lane&7)^(lane>>3)) (inverse swizzle)
    const unsigned int* Msrc = M + (size_t)b * SS * SS
                                 + (size_t)(q0v + (lane >> 3)) * SS
                                 + 32 * kh + 4 * ((lane & 7) ^ (lane >> 3));
    // V staging src per-lane offset (r6-verified granule extract) + NEW bank
    // swizzle: dest slot s_dest=lane&3 at row d=16j+(lane>>2) now holds
    // logical s_log = s_dest ^ ((d>>1)&3) = (lane&3)^((lane>>3)&3); image pos
    // low bits = s_log ^ ((lane>>2)&3).
    const int voff = ((lane >> 2) * 256)
                   + ((kh ^ ((lane >> 4) & 3)) * 64)
                   + ((((lane & 3) ^ ((lane >> 3) & 3) ^ ((lane >> 2) & 3)) * 16));

    auto stage_kv = [&](int bufn, int kt) {
        char* kvb = smem + bufn * KVBUF;
        if (qs == 0) {      // wave-uniform branch: qs=0 waves stage K slice kh
            const char* tK = tKbase + (size_t)kt * TILE_BYTES + 32 * kh * 128;
            #pragma unroll
            for (int j = 0; j < 4; j++)
                GLDS16(tK + j * 1024 + lane * 16, kvb + kh * 4096 + j * 1024);
        } else {            // qs=1 waves stage V slice kh (granule extract)
            const char* tV = tVbase + (size_t)kt * TILE_BYTES;
            #pragma unroll
            for (int j = 0; j < 4; j++)
                GLDS16(tV + j * 4096 + voff, kvb + 16384 + kh * 4096 + j * 1024);
        }
    };
    auto stage_m = [&](int bufn, int kt) {
        char* mb = Mbase + bufn * MBUF + w * 4096;
        const unsigned int* ms = Msrc + (size_t)kt * 128;
        #pragma unroll
        for (int j = 0; j < 4; j++)
            GLDS16(ms + (size_t)j * 8 * SS, mb + j * 1024);
    };

    // prologue: KV(0), M(0), M(1) in flight (12 glds)
    stage_kv(0, 0);
    stage_m(0, 0);
    stage_m(1, 1);

    #pragma unroll 1
    for (int kt = 0; kt < NT_TILES; ++kt) {
        // 1. counted wait: newest 4 = next M batch; retires M(kt) + KV(kt).
        asm volatile("s_waitcnt vmcnt(4)" ::: "memory");
        __builtin_amdgcn_sched_barrier(0);
        // 2. raw barrier (no drain): kt data visible, kt-1 buffers free
        __builtin_amdgcn_s_barrier();
        // 3./4. stages (dead clamped tails target non-live buffers)
        const int kKV = (kt + 1 < NT_TILES) ? kt + 1 : NT_TILES - 1;
        const int kM  = (kt + 2 < NT_TILES) ? kt + 2 : NT_TILES - 1;
        stage_kv((kt + 1) & 1, kKV);
        stage_m((kt + 2) % 3, kM);

        // 5. consume tile kt
        const char* kvb = smem + (kt & 1) * KVBUF;
        const char* mb  = Mbase + (kt % 3) * MBUF + w * 4096;

        bf16x8 ak[4];
        #pragma unroll
        for (int dc = 0; dc < 4; dc++)
            ak[dc] = __builtin_bit_cast(bf16x8, *(const ushort8*)(
                kvb + kh * 4096 + l31 * 128 + (((2 * dc + half) ^ r7) * 16)));
        uint4v mt[4];
        #pragma unroll
        for (int g = 0; g < 4; g++)
            mt[g] = *(const uint4v*)(mb + l31 * 128 + 16 * ((half + 2 * g) ^ r7));
        bf16x8 av[2][2];
        #pragma unroll
        for (int s2 = 0; s2 < 2; s2++)
            #pragma unroll
            for (int dc = 0; dc < 2; dc++) {
                const int vrow = 32 * dc + l31;
                av[s2][dc] = __builtin_bit_cast(bf16x8, *(const ushort8*)(
                    kvb + 16384 + kh * 4096 + vrow * 64 +
                    (((2 * s2 + half) ^ ((l31 >> 1) & 3)) * 16)));
            }

        // QK^T: S^T tile [32k x 32q]
        f32x16 S;
        #pragma unroll
        for (int i = 0; i < 16; i++) S[i] = 0.f;
        #pragma unroll
        for (int dc = 0; dc < 4; dc++)
            S = __builtin_amdgcn_mfma_f32_32x32x16_bf16(ak[dc], bq[dc], S, 0, 0, 0);

        // mask + exp + denominator (C row = e + 8g + 4half)
        float p[16];
        #pragma unroll
        for (int g = 0; g < 4; g++) {
            #pragma unroll
            for (int e = 0; e < 4; e++) {
                const float ev = __expf(S[4 * g + e]);
                const float pv = mt[g][e] ? 1.0f : ev;
                p[4 * g + e] = pv;
                if (g & 1) den1 += pv; else den0 += pv;
            }
        }

        // P*V: B-operand frags via shfl_xor(32), 2 ksubs (r0-proven)
        #pragma unroll
        for (int s2 = 0; s2 < 2; s2++) {
            const unsigned o0 = pk2(p[8 * s2 + 0], p[8 * s2 + 1]);
            const unsigned o1 = pk2(p[8 * s2 + 2], p[8 * s2 + 3]);
            const unsigned o2 = pk2(p[8 * s2 + 4], p[8 * s2 + 5]);
            const unsigned o3 = pk2(p[8 * s2 + 6], p[8 * s2 + 7]);
            const unsigned s0 = half ? o0 : o2;
            const unsigned s1 = half ? o1 : o3;
            const unsigned r0 = (unsigned)__shfl_xor((int)s0, 32, 64);
            const unsigned r1 = (unsigned)__shfl_xor((int)s1, 32, 64);
            uint4 bu;
            bu.x = half ? r0 : o0;
            bu.y = half ? r1 : o1;
            bu.z = half ? o2 : r0;
            bu.w = half ? o3 : r1;
            const bf16x8 bp = __builtin_bit_cast(bf16x8, bu);
            On0 = __builtin_amdgcn_mfma_f32_32x32x16_bf16(av[s2][0], bp, On0, 0, 0, 0);
            On1 = __builtin_amdgcn_mfma_f32_32x32x16_bf16(av[s2][1], bp, On1, 0, 0, 0);
        }
    }

    // ---- epilogue: lane halves, then 4-way kh reduction per qs group ----
    const float den_acc = den0 + den1;
    const float den_tot = den_acc + __shfl_xor(den_acc, 32, 64);

    __syncthreads();   // full drain (incl. dead tail stages); bufs -> red/denx
    if (kh != 0) {
        #pragma unroll
        for (int dc = 0; dc < 2; dc++)
            #pragma unroll
            for (int g = 0; g < 4; g++) {
                const f32x16& Oc = dc ? On1 : On0;
                float4 st;
                st.x = Oc[4 * g + 0]; st.y = Oc[4 * g + 1];
                st.z = Oc[4 * g + 2]; st.w = Oc[4 * g + 3];
                *(float4*)((char*)red + qs * 24576 + (kh - 1) * 8192 +
                           (dc * 4 + g) * 1024 + lane * 16) = st;
            }
        if (lane < 32) denx[w * 32 + l31] = den_tot;
    }
    __syncthreads();
    if (kh == 0) {
        const float inv = 1.0f / (den_tot + denx[(qs * 4 + 1) * 32 + l31]
                                          + denx[(qs * 4 + 2) * 32 + l31]
                                          + denx[(qs * 4 + 3) * 32 + l31]);
        float* Og = O + ((size_t)b * SS + q0v + qrow) * DD;
        #pragma unroll
        for (int dc = 0; dc < 2; dc++)
            #pragma unroll
            for (int g = 0; g < 4; g++) {
                const f32x16& Oc = dc ? On1 : On0;
                float4 st;
                st.x = Oc[4 * g + 0]; st.y = Oc[4 * g + 1];
                st.z = Oc[4 * g + 2]; st.w = Oc[4 * g + 3];
                #pragma unroll
                for (int w2 = 0; w2 < 3; w2++) {
                    const float4 pr = *(const float4*)((char*)red + qs * 24576 +
                                        w2 * 8192 + (dc * 4 + g) * 1024 + lane * 16);
                    st.x += pr.x; st.y += pr.y; st.z += pr.z; st.w += pr.w;
                }
                st.x *= inv; st.y *= inv; st.z *= inv; st.w *= inv;
                // d = e + 8g + 4half + 32dc  (C-row formula)
                *(float4*)(Og + 32 * dc + 8 * g + 4 * half) = st;
            }
    }
}

extern "C" void kernel_launch(void* const* d_in, const int* in_sizes, int n_in,
                              void* d_out, int out_size, void* d_ws, size_t ws_size,
                              hipStream_t stream) {
    const float* q = (const float*)d_in[0];
    const float* k = (const float*)d_in[1];
    const float* v = (const float*)d_in[2];
    const unsigned int* m = (const unsigned int*)d_in[3];
    float* out = (float*)d_out;

    // workspace: 4 MB K images + 4 MB V images (bf16, swizzled tile layout)
    char* wsK = (char*)d_ws;
    char* wsV = wsK + (size_t)BB * NT_TILES * TILE_BYTES;

    dim3 pgrid(NT_TILES, BB);           // 256 blocks
    prepack_kernel<<<pgrid, 256, 0, stream>>>(k, v, wsK, wsV);

    dim3 grid(SS / 64, BB);             // 512 blocks x 512 thr -> 1/CU, 2 rounds
    sdpa_mfma_kernel<<<grid, 512, 0, stream>>>(q, wsK, wsV, m, out);
}